// Round 22
// baseline (651.189 us; speedup 1.0000x reference)
//
#include <hip/hip_runtime.h>

#define DEV __device__ __forceinline__

typedef __bf16 bf16x8 __attribute__((ext_vector_type(8)));
typedef float  f32x4  __attribute__((ext_vector_type(4)));
typedef unsigned short u16x8 __attribute__((ext_vector_type(8)));
typedef unsigned short u16x4 __attribute__((ext_vector_type(4)));
typedef long  longx2 __attribute__((ext_vector_type(2)));

DEV float b2f(unsigned short u) {
    unsigned int t = ((unsigned int)u) << 16;
    return __uint_as_float(t);
}
DEV unsigned short f2b(float f) {
    unsigned int u = __float_as_uint(f);
    unsigned int r = (u + 0x7FFFu + ((u >> 16) & 1u)) >> 16;
    return (unsigned short)r;
}
DEV unsigned char f2f8(float f) {
    return (unsigned char)(__builtin_amdgcn_cvt_pk_fp8_f32(f, f, 0, false) & 0xff);
}

// k-interleaved fp8 file layout (for BK=64 GEMM inputs): within each 64B K-block,
// slot order {0,4,1,5,2,6,3,7} -> file 16B chunk c holds k-slots {c, c+4}.
DEV int kpos(int c) {
    int s = (c >> 3) & 7;
    return (c & ~63) | ((((s & 3) << 1) | (s >> 2)) << 3) | (c & 7);
}

DEV void gload_lds16(const void* g, void* l) {
    __builtin_amdgcn_global_load_lds(
        (const __attribute__((address_space(1))) void*)g,
        (__attribute__((address_space(3))) void*)l, 16, 0, 0);
}

// dest window-row -> source/dest token index (roll by SS=3, window 7x7, 56x56, 64 win/batch)
DEV size_t win_to_tok(int row) {
    int w = row / 49, t = row - w * 49;
    int b  = w >> 6, widx = w & 63;
    int wi = widx >> 3, wj = widx & 7;
    int ti = t / 7, tj = t - ti * 7;
    int hh = wi * 7 + ti + 3; if (hh >= 56) hh -= 56;
    int ww = wj * 7 + tj + 3; if (ww >= 56) ww -= 56;
    return (size_t)b * 3136 + (size_t)hh * 56 + ww;
}

// ---------------- row -> token map (for proj epilogue) ----------------
__global__ void tokmap_build(int* __restrict__ tm, int T) {
    int i = blockIdx.x * 256 + threadIdx.x;
    if (i < T) tm[i] = (int)win_to_tok(i);
}

// ---------------- weight prep: fp32 [K][N] -> fp8 e4m3 [N][K] (k-interleaved) ----------------
__global__ void wprep8(const float* __restrict__ src, unsigned char* __restrict__ dst,
                       int K, int N) {
    int idx = blockIdx.x * 256 + threadIdx.x;
    if (idx >= K * N) return;
    int k = idx / N, n = idx - k * N;
    dst[(size_t)n * K + kpos(k)] = f2f8(src[idx]);
}

// ---------------- bias table: [cls 4][h 12][row 64][col 64] fp32 ----------------
__global__ void btab_build(const int* __restrict__ rel_idx, const float* __restrict__ rpb,
                           float* __restrict__ tab) {
    int idx = blockIdx.x * 256 + threadIdx.x;
    if (idx >= 4 * 12 * 64 * 64) return;
    int col = idx & 63, row = (idx >> 6) & 63;
    int h = (idx >> 12) % 12, cls = idx / (12 * 4096);
    float v;
    if (row >= 49 || col >= 49) {
        v = -10000.f;
    } else {
        v = rpb[rel_idx[row * 49 + col] * 12 + h];
        int ti = row / 7, tj = row - (row / 7) * 7;
        int si = col / 7, sj = col - (col / 7) * 7;
        int lq = ((cls & 2) ? (ti < 4 ? 1 : 2) : 0) * 3 + ((cls & 1) ? (tj < 4 ? 1 : 2) : 0);
        int lk = ((cls & 2) ? (si < 4 ? 1 : 2) : 0) * 3 + ((cls & 1) ? (sj < 4 ? 1 : 2) : 0);
        if (lq != lk) v -= 100.f;
    }
    tab[idx] = v;
}

// ---------------- LayerNorm (+optional gather), fp32 -> fp8 (k-interleaved) ----------------
template <int REMAP>
__global__ __launch_bounds__(256) void ln_kernel(const float* __restrict__ x,
                                                 const float* __restrict__ g,
                                                 const float* __restrict__ b,
                                                 unsigned char* __restrict__ out,
                                                 int rows) {
    int r = blockIdx.x * 4 + (threadIdx.x >> 6);
    int lane = threadIdx.x & 63;
    if (r >= rows) return;
    size_t src = REMAP ? win_to_tok(r) : (size_t)r;
    const float* xp = x + src * 384;
    float v[6];
    float s = 0.f;
#pragma unroll
    for (int i = 0; i < 6; ++i) { v[i] = xp[i * 64 + lane]; s += v[i]; }
#pragma unroll
    for (int off = 32; off; off >>= 1) s += __shfl_xor(s, off, 64);
    float mu = s * (1.f / 384.f);
    float q = 0.f;
#pragma unroll
    for (int i = 0; i < 6; ++i) { float d = v[i] - mu; q += d * d; }
#pragma unroll
    for (int off = 32; off; off >>= 1) q += __shfl_xor(q, off, 64);
    float inv = rsqrtf(q * (1.f / 384.f) + 1e-5f);
    unsigned char* op = out + (size_t)r * 384;
#pragma unroll
    for (int i = 0; i < 6; ++i) {
        int c = i * 64 + lane;
        op[kpos(c)] = f2f8((v[i] - mu) * inv * g[c] + b[c]);
    }
}

// ---------------- full-K fp8 GEMM (K=384): 64x128 tile, 8 waves, ZERO intra-loop syncs ----------
// MODE 0: out fp8 PLAIN (QKV) | 1: resid+C+bias via tokmap, fp32 (proj) | 2: fp8 k-int gelu (FFN1)
template <int MODE>
__global__ __launch_bounds__(512, 2) void gemm_f8_fullk(const unsigned char* __restrict__ A,
                                                        const unsigned char* __restrict__ Bt,
                                                        int M, int N, int K,
                                                        const float* __restrict__ bias,
                                                        const float* __restrict__ resid,
                                                        const int* __restrict__ tokmap,
                                                        unsigned char* __restrict__ outb8,
                                                        float* __restrict__ outf) {
    __shared__ unsigned char Als[64 * 384];    // 24 KB
    __shared__ unsigned char Bls[128 * 384];   // 48 KB
    const int tid = threadIdx.x;               // 0..511
    const int wid = tid >> 6, lane = tid & 63;
    const int ntile = N >> 7;

    int bid = blockIdx.x;
    int nwg = gridDim.x;
    int swb = ((nwg & 7) == 0) ? ((bid & 7) * (nwg >> 3) + (bid >> 3)) : bid;
    const int mt = swb / ntile, nt = swb - mt * ntile;

    const unsigned char* Abase = A  + (size_t)(mt * 64) * K;
    const unsigned char* Bbase = Bt + (size_t)(nt * 128) * K;

    {
        int rB = tid >> 2;
        int gpB = (tid & 3) ^ ((rB >> 1) & 3);
#pragma unroll
        for (int kb = 0; kb < 6; ++kb)
            gload_lds16(Bbase + (size_t)rB * K + kb * 64 + gpB * 16, &Bls[kb * 8192 + tid * 16]);
        if (tid < 256) {
            int rA = tid >> 2;
            int gpA = (tid & 3) ^ ((rA >> 1) & 3);
#pragma unroll
            for (int kb = 0; kb < 6; ++kb)
                gload_lds16(Abase + (size_t)rA * K + kb * 64 + gpA * 16, &Als[kb * 4096 + tid * 16]);
        }
    }
    asm volatile("s_waitcnt vmcnt(0)" ::: "memory");
    __builtin_amdgcn_s_barrier();

    const int fr = lane & 15, kq = lane >> 4;
    const int cb = (kq ^ ((fr >> 1) & 3)) << 4;

    f32x4 acc[4] = {};
#pragma unroll
    for (int kb = 0; kb < 6; ++kb) {
        longx2 a[4], b;
        b = *(const longx2*)(&Bls[kb * 8192 + (wid * 16 + fr) * 64 + cb]);
#pragma unroll
        for (int m = 0; m < 4; ++m)
            a[m] = *(const longx2*)(&Als[kb * 4096 + (m * 16 + fr) * 64 + cb]);
#pragma unroll
        for (int ks = 0; ks < 2; ++ks)
#pragma unroll
            for (int m = 0; m < 4; ++m)
                acc[m] = __builtin_amdgcn_mfma_f32_16x16x32_fp8_fp8(b[ks], a[m][ks], acc[m], 0, 0, 0);
    }

    const int row0 = mt * 64;
    const int col0 = nt * 128 + wid * 16;
    const int rl = lane & 15;
    const int cq = (lane >> 4) << 2;
    const int col = col0 + cq;
#pragma unroll
    for (int m = 0; m < 4; ++m) {
        int row = row0 + m * 16 + rl;
        f32x4 v = acc[m];
        if constexpr (MODE == 0) {
            int pk = 0;
            pk = __builtin_amdgcn_cvt_pk_fp8_f32(v[0], v[1], pk, false);
            pk = __builtin_amdgcn_cvt_pk_fp8_f32(v[2], v[3], pk, true);
            *(int*)(outb8 + (size_t)row * N + col) = pk;
        } else if constexpr (MODE == 1) {
            size_t o = (size_t)tokmap[row] * 384 + col;
            f32x4 rv = *(const f32x4*)&resid[o];
            f32x4 bb = *(const f32x4*)&bias[col];
            f32x4 ov = rv + v + bb;
            *(f32x4*)&outf[o] = ov;
        } else {
            f32x4 bb = *(const f32x4*)&bias[col];
            float g4[4];
#pragma unroll
            for (int r = 0; r < 4; ++r) {
                float t2 = v[r] + bb[r];
                float e  = __expf(-1.702f * t2);
                g4[r] = t2 * __builtin_amdgcn_rcpf(1.f + e);
            }
            int pk = 0;
            pk = __builtin_amdgcn_cvt_pk_fp8_f32(g4[0], g4[1], pk, false);
            pk = __builtin_amdgcn_cvt_pk_fp8_f32(g4[2], g4[3], pk, true);
            *(int*)(outb8 + (size_t)row * N + kpos(col)) = pk;
        }
    }
}

// ---------------- fp8 ring GEMM (FFN2, K=1536): 8-wave 64x128 tile, single-barrier ring ----------
// NBUF=4/DEPTH=2, BK=64; LDS 48 KB -> 3 blocks/CU x 8 waves = 6 waves/SIMD.
// Staging uneven: waves 0-3 carry A+B (2 loads/stage), waves 4-7 B only (1) ->
// per-wave-uniform counted vmcnt; barrier proves tile residency for all.
template <int NBUF, int DEPTH>
__global__ __launch_bounds__(512, 4) void gemm_f8_ring8(const unsigned char* __restrict__ A,
                                                        const unsigned char* __restrict__ Bt,
                                                        int M, int N, int K,
                                                        const float* __restrict__ bias,
                                                        const float* __restrict__ resid,
                                                        float* __restrict__ outf) {
    static_assert(NBUF >= DEPTH + 2, "single-barrier ring needs NBUF >= DEPTH+2");
    __shared__ unsigned char As[NBUF][64 * 64];    // 4 KB each
    __shared__ unsigned char Bs[NBUF][128 * 64];   // 8 KB each
    const int tid = threadIdx.x;                   // 0..511
    const int wid = tid >> 6, lane = tid & 63;
    const int ntile = N >> 7;

    int bid = blockIdx.x;
    int nwg = gridDim.x;
    int swb = ((nwg & 7) == 0) ? ((bid & 7) * (nwg >> 3) + (bid >> 3)) : bid;
    const int mt = swb / ntile, nt = swb - mt * ntile;

    f32x4 acc[4] = {};

    const unsigned char* Abase = A  + (size_t)(mt * 64) * K;
    const unsigned char* Bbase = Bt + (size_t)(nt * 128) * K;

    auto stage = [&](int buf, int k0) {
        int rB = tid >> 2;
        int gpB = (tid & 3) ^ ((rB >> 1) & 3);
        gload_lds16(Bbase + (size_t)rB * K + k0 + gpB * 16, &Bs[buf][tid * 16]);
        if (tid < 256) {
            int rA = tid >> 2;
            int gpA = (tid & 3) ^ ((rA >> 1) & 3);
            gload_lds16(Abase + (size_t)rA * K + k0 + gpA * 16, &As[buf][tid * 16]);
        }
    };

    const int fr = lane & 15, kq = lane >> 4;
    const int cb = (kq ^ ((fr >> 1) & 3)) << 4;
    const int rowB = wid * 16 + fr;

    const int nk = K >> 6;   // 24 for K=1536
    stage(0, 0);
    stage(1, 64);

    for (int t = 0; t < nk; ++t) {
        const int cur = t % NBUF;
        if (t + DEPTH < nk) {
            stage((t + DEPTH) % NBUF, (t + DEPTH) << 6);
            if (wid < 4) { asm volatile("s_waitcnt vmcnt(4)" ::: "memory"); }
            else         { asm volatile("s_waitcnt vmcnt(2)" ::: "memory"); }
        } else if (t + 1 < nk) {
            if (wid < 4) { asm volatile("s_waitcnt vmcnt(2)" ::: "memory"); }
            else         { asm volatile("s_waitcnt vmcnt(1)" ::: "memory"); }
        } else {
            asm volatile("s_waitcnt vmcnt(0)" ::: "memory");
        }
        __builtin_amdgcn_s_barrier();   // tile t resident for every wave; releases ring slot

        longx2 a[4], b;
        b = *(const longx2*)(&Bs[cur][rowB * 64 + cb]);
#pragma unroll
        for (int m = 0; m < 4; ++m)
            a[m] = *(const longx2*)(&As[cur][(m * 16 + fr) * 64 + cb]);
#pragma unroll
        for (int ks = 0; ks < 2; ++ks)
#pragma unroll
            for (int m = 0; m < 4; ++m)
                acc[m] = __builtin_amdgcn_mfma_f32_16x16x32_fp8_fp8(b[ks], a[m][ks], acc[m], 0, 0, 0);

        asm volatile("s_waitcnt lgkmcnt(0)" ::: "memory");
    }

    const int row0 = mt * 64;
    const int col  = nt * 128 + wid * 16 + ((lane >> 4) << 2);
    const int rl   = lane & 15;
#pragma unroll
    for (int m = 0; m < 4; ++m) {
        int row = row0 + m * 16 + rl;
        f32x4 v = acc[m];
        size_t o = (size_t)row * N + col;
        f32x4 rv = *(const f32x4*)&resid[o];
        f32x4 bb = *(const f32x4*)&bias[col];
        f32x4 ov = rv + v + bb;
        *(f32x4*)&outf[o] = ov;
    }
}

// ---------------- MFMA attention: fp8 QK^T, bf16 PV; O out fp8 k-interleaved ----------------
__global__ __launch_bounds__(256, 2) void attn_kernel(const unsigned char* __restrict__ QKV8,
                                                      const float* __restrict__ Btab,
                                                      unsigned char* __restrict__ O8) {
    __shared__ char lds[8192 + 16384 + 32768];   // Kl 8K | Vl 16K | Pl 32K = 56 KB
    char* Kl = lds;
    char* Vl = lds + 8192;
    char* Pl = lds + 24576;

    const int w   = blockIdx.x;
    const int tid = threadIdx.x, wid = tid >> 6, lane = tid & 63;
    const int fr  = lane & 15, kq = lane >> 4;
    const size_t base = (size_t)w * 49 * 1152;
    const int widx = w & 63, wi = widx >> 3, wj = widx & 7;
    const int cls = ((wi == 7) ? 2 : 0) | ((wj == 7) ? 1 : 0);
    const float* tb = Btab + (size_t)cls * 12 * 4096;
    constexpr float SCL = 0.17677669529663687f;

    for (int R = 0; R < 3; ++R) {
        if (R) __syncthreads();
        {
            f32x4 z = {};
#pragma unroll
            for (int j = 0; j < 6; ++j) *(f32x4*)(lds + j * 4096 + tid * 16) = z;
        }
        __syncthreads();
        {
            int hh = tid >> 6, h = R * 4 + hh;
#pragma unroll
            for (int it = 0; it < 4; ++it) {
                int i = (tid & 63) + it * 64;
                if (i < 196) {
                    int m = i >> 2, c = i & 3;
                    long k8 = *(const long*)(QKV8 + base + (size_t)m * 1152 + 384 + h * 32 + c * 8);
                    int s = c ^ (m & 3) ^ ((m >> 2) & 3);
                    *(long*)(Kl + hh * 2048 + m * 32 + s * 8) = k8;
                    long v8 = *(const long*)(QKV8 + base + (size_t)m * 1152 + 768 + h * 32 + c * 8);
                    int lo = (int)v8, hi = (int)(v8 >> 32);
                    float vf[8];
                    vf[0] = __builtin_amdgcn_cvt_f32_fp8(lo, 0);
                    vf[1] = __builtin_amdgcn_cvt_f32_fp8(lo, 1);
                    vf[2] = __builtin_amdgcn_cvt_f32_fp8(lo, 2);
                    vf[3] = __builtin_amdgcn_cvt_f32_fp8(lo, 3);
                    vf[4] = __builtin_amdgcn_cvt_f32_fp8(hi, 0);
                    vf[5] = __builtin_amdgcn_cvt_f32_fp8(hi, 1);
                    vf[6] = __builtin_amdgcn_cvt_f32_fp8(hi, 2);
                    vf[7] = __builtin_amdgcn_cvt_f32_fp8(hi, 3);
#pragma unroll
                    for (int j = 0; j < 8; ++j) {
                        int d = c * 8 + j;
                        *(unsigned short*)(Vl + hh * 4096 + d * 128 +
                                           (((m >> 3) ^ (d & 7)) * 16) + (m & 7) * 2) = f2b(vf[j]);
                    }
                }
            }
        }
        __syncthreads();

        const int h = R * 4 + wid;
        const float* tbh = tb + h * 4096;

        long aq[4], bk[4];
#pragma unroll
        for (int mi = 0; mi < 4; ++mi) {
            int row = mi * 16 + fr; if (row > 48) row = 48;
            aq[mi] = *(const long*)(QKV8 + base + (size_t)row * 1152 + h * 32 + kq * 8);
        }
#pragma unroll
        for (int ni = 0; ni < 4; ++ni) {
            int rk = ni * 16 + fr;
            bk[ni] = *(const long*)(Kl + wid * 2048 + rk * 32 +
                                    ((kq ^ (rk & 3) ^ ((rk >> 2) & 3)) * 8));
        }
        f32x4 s[4][4] = {};
#pragma unroll
        for (int mi = 0; mi < 4; ++mi)
#pragma unroll
            for (int ni = 0; ni < 4; ++ni)
                s[mi][ni] = __builtin_amdgcn_mfma_f32_16x16x32_fp8_fp8(bk[ni], aq[mi], s[mi][ni], 0, 0, 0);

        float linv_[4];
#pragma unroll
        for (int mi = 0; mi < 4; ++mi) {
            int row = mi * 16 + fr;
            const float* tr = tbh + row * 64 + kq * 4;
            f32x4 sv[4];
            float mx = -1e30f;
#pragma unroll
            for (int ni = 0; ni < 4; ++ni) {
                f32x4 bb = *(const f32x4*)&tr[ni * 16];
                sv[ni] = s[mi][ni] * SCL + bb;
                mx = fmaxf(mx, fmaxf(fmaxf(sv[ni][0], sv[ni][1]), fmaxf(sv[ni][2], sv[ni][3])));
            }
            mx = fmaxf(mx, __shfl_xor(mx, 16, 64));
            mx = fmaxf(mx, __shfl_xor(mx, 32, 64));
            float sm = 0.f;
#pragma unroll
            for (int ni = 0; ni < 4; ++ni)
#pragma unroll
                for (int r = 0; r < 4; ++r) { sv[ni][r] = __expf(sv[ni][r] - mx); sm += sv[ni][r]; }
            sm += __shfl_xor(sm, 16, 64);
            sm += __shfl_xor(sm, 32, 64);
            linv_[mi] = __builtin_amdgcn_rcpf(sm);
#pragma unroll
            for (int ni = 0; ni < 4; ++ni) {
                int colb = ni * 16 + kq * 4;
                int phys = (colb >> 3) ^ (row & 7);
                u16x4 pk;
#pragma unroll
                for (int r = 0; r < 4; ++r) pk[r] = f2b(sv[ni][r]);
                *(u16x4*)(Pl + wid * 8192 + row * 128 + phys * 16 + (colb & 7) * 2) = pk;
            }
        }
        asm volatile("s_waitcnt lgkmcnt(0)" ::: "memory");
        __builtin_amdgcn_sched_barrier(0);

        f32x4 oacc[4][2] = {};
#pragma unroll
        for (int sl = 0; sl < 2; ++sl) {
            bf16x8 bv[2];
#pragma unroll
            for (int ni = 0; ni < 2; ++ni) {
                int d = ni * 16 + fr;
                bv[ni] = *(const bf16x8*)(Vl + wid * 4096 + d * 128 + (((sl * 4 + kq) ^ (d & 7)) * 16));
            }
#pragma unroll
            for (int mi = 0; mi < 4; ++mi) {
                int row = mi * 16 + fr;
                bf16x8 ap = *(const bf16x8*)(Pl + wid * 8192 + row * 128 + (((sl * 4 + kq) ^ (row & 7)) * 16));
#pragma unroll
                for (int ni = 0; ni < 2; ++ni)
                    oacc[mi][ni] = __builtin_amdgcn_mfma_f32_16x16x32_bf16(bv[ni], ap, oacc[mi][ni], 0, 0, 0);
            }
        }

#pragma unroll
        for (int mi = 0; mi < 4; ++mi) {
            int row = mi * 16 + fr;
            if (row < 49) {
                float li = linv_[mi];
                unsigned char* opb = O8 + (size_t)(w * 49 + row) * 384;
#pragma unroll
                for (int ni = 0; ni < 2; ++ni) {
                    int c = h * 32 + ni * 16 + kq * 4;
                    int pk = 0;
                    pk = __builtin_amdgcn_cvt_pk_fp8_f32(oacc[mi][ni][0] * li, oacc[mi][ni][1] * li, pk, false);
                    pk = __builtin_amdgcn_cvt_pk_fp8_f32(oacc[mi][ni][2] * li, oacc[mi][ni][3] * li, pk, true);
                    *(int*)(opb + kpos(c)) = pk;
                }
            }
        }
    }
}

extern "C" void kernel_launch(void* const* d_in, const int* in_sizes, int n_in,
                              void* d_out, int out_size, void* d_ws, size_t ws_size,
                              hipStream_t stream) {
    const float* x     = (const float*)d_in[0];
    const int*   rel   = (const int*)  d_in[3];
    const float* rpb   = (const float*)d_in[4];
    const float* qkvw  = (const float*)d_in[5];
    const float* projw = (const float*)d_in[6];
    const float* projb = (const float*)d_in[7];
    const float* n1g   = (const float*)d_in[8];
    const float* n1b   = (const float*)d_in[9];
    const float* n2g   = (const float*)d_in[10];
    const float* n2b   = (const float*)d_in[11];
    const float* w1    = (const float*)d_in[12];
    const float* b1    = (const float*)d_in[13];
    const float* w2    = (const float*)d_in[14];
    const float* b2    = (const float*)d_in[15];
    float* out = (float*)d_out;

    const int T = in_sizes[0] / 384;   // 100352

    char* ws = (char*)d_ws;
    size_t off = 0;
    auto alloc = [&](size_t bytes) {
        char* p = ws + off;
        off += (bytes + 255) & ~(size_t)255;
        return p;
    };
    unsigned char* Wq8  = (unsigned char*)alloc((size_t)1152 * 384);
    unsigned char* Wp8  = (unsigned char*)alloc((size_t)384 * 384);
    unsigned char* W18  = (unsigned char*)alloc((size_t)1536 * 384);
    unsigned char* W28  = (unsigned char*)alloc((size_t)384 * 1536);
    float*         Btab = (float*)       alloc((size_t)4 * 12 * 4096 * 4);
    int*           Tmap = (int*)         alloc((size_t)T * 4);
    unsigned char* slotA = (unsigned char*)alloc((size_t)T * 384);    // X1_8 -> O8 -> X2_8
    unsigned char* slotB = (unsigned char*)alloc((size_t)T * 1536);   // QKV8 -> F8

    unsigned char* X1   = slotA;
    unsigned char* O8   = slotA;
    unsigned char* X2   = slotA;
    unsigned char* QKV8 = slotB;
    unsigned char* F8   = slotB;
    float*         Hh   = out;

    wprep8<<<dim3((1152 * 384 + 255) / 256), 256, 0, stream>>>(qkvw, Wq8, 384, 1152);
    wprep8<<<dim3((384 * 384 + 255) / 256),  256, 0, stream>>>(projw, Wp8, 384, 384);
    wprep8<<<dim3((384 * 1536 + 255) / 256), 256, 0, stream>>>(w1, W18, 384, 1536);
    wprep8<<<dim3((1536 * 384 + 255) / 256), 256, 0, stream>>>(w2, W28, 1536, 384);
    btab_build<<<dim3((4 * 12 * 4096 + 255) / 256), 256, 0, stream>>>(rel, rpb, Btab);
    tokmap_build<<<dim3((T + 255) / 256), 256, 0, stream>>>(Tmap, T);

    // LN1 + shifted-window gather -> X1 (fp8 k-interleaved)
    ln_kernel<1><<<dim3(T / 4), 256, 0, stream>>>(x, n1g, n1b, X1, T);
    // QKV projection -> QKV8 (fp8 PLAIN; full-K 8-wave)
    gemm_f8_fullk<0><<<dim3((T / 64) * (1152 / 128)), 512, 0, stream>>>(
        X1, Wq8, T, 1152, 384, nullptr, nullptr, nullptr, QKV8, nullptr);
    // MFMA windowed attention (fp8 QK^T, bf16 PV) -> O8 (fp8 k-interleaved)
    attn_kernel<<<dim3(T / 49), 256, 0, stream>>>(QKV8, Btab, O8);
    // proj + bias + tokmap remap + residual -> Hh (= d_out, fp32; full-K 8-wave)
    gemm_f8_fullk<1><<<dim3((T / 64) * (384 / 128)), 512, 0, stream>>>(
        O8, Wp8, T, 384, 384, projb, x, Tmap, nullptr, Hh);
    // LN2 -> X2 (fp8 k-interleaved)
    ln_kernel<0><<<dim3(T / 4), 256, 0, stream>>>(Hh, n2g, n2b, X2, T);
    // FFN1 + bias + sigmoid-GELU -> F8 (fp8 k-interleaved; full-K 8-wave)
    gemm_f8_fullk<2><<<dim3((T / 64) * (1536 / 128)), 512, 0, stream>>>(
        X2, W18, T, 1536, 384, b1, nullptr, nullptr, F8, nullptr);
    // FFN2 + bias + residual -> out (fp32, in-place RMW; 8-wave single-barrier ring)
    gemm_f8_ring8<4, 2><<<dim3((T / 64) * (384 / 128)), 512, 0, stream>>>(
        F8, W28, T, 384, 1536, b2, Hh, out);
}

// Round 23
// 639.711 us; speedup vs baseline: 1.0179x; 1.0179x over previous
//
#include <hip/hip_runtime.h>

#define DEV __device__ __forceinline__

typedef __bf16 bf16x8 __attribute__((ext_vector_type(8)));
typedef float  f32x4  __attribute__((ext_vector_type(4)));
typedef unsigned short u16x8 __attribute__((ext_vector_type(8)));
typedef unsigned short u16x4 __attribute__((ext_vector_type(4)));
typedef long  longx2 __attribute__((ext_vector_type(2)));

DEV float b2f(unsigned short u) {
    unsigned int t = ((unsigned int)u) << 16;
    return __uint_as_float(t);
}
DEV unsigned short f2b(float f) {
    unsigned int u = __float_as_uint(f);
    unsigned int r = (u + 0x7FFFu + ((u >> 16) & 1u)) >> 16;
    return (unsigned short)r;
}
DEV unsigned char f2f8(float f) {
    return (unsigned char)(__builtin_amdgcn_cvt_pk_fp8_f32(f, f, 0, false) & 0xff);
}

// k-interleaved fp8 file layout (for BK=64 GEMM inputs): within each 64B K-block,
// slot order {0,4,1,5,2,6,3,7} -> file 16B chunk c holds k-slots {c, c+4}.
DEV int kpos(int c) {
    int s = (c >> 3) & 7;
    return (c & ~63) | ((((s & 3) << 1) | (s >> 2)) << 3) | (c & 7);
}

DEV void gload_lds16(const void* g, void* l) {
    __builtin_amdgcn_global_load_lds(
        (const __attribute__((address_space(1))) void*)g,
        (__attribute__((address_space(3))) void*)l, 16, 0, 0);
}

// dest window-row -> source/dest token index (roll by SS=3, window 7x7, 56x56, 64 win/batch)
DEV size_t win_to_tok(int row) {
    int w = row / 49, t = row - w * 49;
    int b  = w >> 6, widx = w & 63;
    int wi = widx >> 3, wj = widx & 7;
    int ti = t / 7, tj = t - ti * 7;
    int hh = wi * 7 + ti + 3; if (hh >= 56) hh -= 56;
    int ww = wj * 7 + tj + 3; if (ww >= 56) ww -= 56;
    return (size_t)b * 3136 + (size_t)hh * 56 + ww;
}

// ---------------- row -> token map (for proj epilogue) ----------------
__global__ void tokmap_build(int* __restrict__ tm, int T) {
    int i = blockIdx.x * 256 + threadIdx.x;
    if (i < T) tm[i] = (int)win_to_tok(i);
}

// ---------------- weight prep: fp32 [K][N] -> fp8 e4m3 [N][K] (k-interleaved) ----------------
__global__ void wprep8(const float* __restrict__ src, unsigned char* __restrict__ dst,
                       int K, int N) {
    int idx = blockIdx.x * 256 + threadIdx.x;
    if (idx >= K * N) return;
    int k = idx / N, n = idx - k * N;
    dst[(size_t)n * K + kpos(k)] = f2f8(src[idx]);
}

// ---------------- bias table: [cls 4][h 12][row 64][col 64] fp32 ----------------
__global__ void btab_build(const int* __restrict__ rel_idx, const float* __restrict__ rpb,
                           float* __restrict__ tab) {
    int idx = blockIdx.x * 256 + threadIdx.x;
    if (idx >= 4 * 12 * 64 * 64) return;
    int col = idx & 63, row = (idx >> 6) & 63;
    int h = (idx >> 12) % 12, cls = idx / (12 * 4096);
    float v;
    if (row >= 49 || col >= 49) {
        v = -10000.f;
    } else {
        v = rpb[rel_idx[row * 49 + col] * 12 + h];
        int ti = row / 7, tj = row - (row / 7) * 7;
        int si = col / 7, sj = col - (col / 7) * 7;
        int lq = ((cls & 2) ? (ti < 4 ? 1 : 2) : 0) * 3 + ((cls & 1) ? (tj < 4 ? 1 : 2) : 0);
        int lk = ((cls & 2) ? (si < 4 ? 1 : 2) : 0) * 3 + ((cls & 1) ? (sj < 4 ? 1 : 2) : 0);
        if (lq != lk) v -= 100.f;
    }
    tab[idx] = v;
}

// ---------------- LayerNorm (+optional gather), fp32 -> fp8 (k-interleaved) ----------------
template <int REMAP>
__global__ __launch_bounds__(256) void ln_kernel(const float* __restrict__ x,
                                                 const float* __restrict__ g,
                                                 const float* __restrict__ b,
                                                 unsigned char* __restrict__ out,
                                                 int rows) {
    int r = blockIdx.x * 4 + (threadIdx.x >> 6);
    int lane = threadIdx.x & 63;
    if (r >= rows) return;
    size_t src = REMAP ? win_to_tok(r) : (size_t)r;
    const float* xp = x + src * 384;
    float v[6];
    float s = 0.f;
#pragma unroll
    for (int i = 0; i < 6; ++i) { v[i] = xp[i * 64 + lane]; s += v[i]; }
#pragma unroll
    for (int off = 32; off; off >>= 1) s += __shfl_xor(s, off, 64);
    float mu = s * (1.f / 384.f);
    float q = 0.f;
#pragma unroll
    for (int i = 0; i < 6; ++i) { float d = v[i] - mu; q += d * d; }
#pragma unroll
    for (int off = 32; off; off >>= 1) q += __shfl_xor(q, off, 64);
    float inv = rsqrtf(q * (1.f / 384.f) + 1e-5f);
    unsigned char* op = out + (size_t)r * 384;
#pragma unroll
    for (int i = 0; i < 6; ++i) {
        int c = i * 64 + lane;
        op[kpos(c)] = f2f8((v[i] - mu) * inv * g[c] + b[c]);
    }
}

// ---------------- full-K fp8 GEMM (K=384): 64x128 tile, 8 waves, ZERO intra-loop syncs ----------
// MODE 0: out fp8 PLAIN (QKV) | 1: resid+C+bias via tokmap, fp32 (proj) | 2: fp8 k-int gelu (FFN1)
template <int MODE>
__global__ __launch_bounds__(512, 2) void gemm_f8_fullk(const unsigned char* __restrict__ A,
                                                        const unsigned char* __restrict__ Bt,
                                                        int M, int N, int K,
                                                        const float* __restrict__ bias,
                                                        const float* __restrict__ resid,
                                                        const int* __restrict__ tokmap,
                                                        unsigned char* __restrict__ outb8,
                                                        float* __restrict__ outf) {
    __shared__ unsigned char Als[64 * 384];    // 24 KB
    __shared__ unsigned char Bls[128 * 384];   // 48 KB
    const int tid = threadIdx.x;               // 0..511
    const int wid = tid >> 6, lane = tid & 63;
    const int ntile = N >> 7;

    int bid = blockIdx.x;
    int nwg = gridDim.x;
    int swb = ((nwg & 7) == 0) ? ((bid & 7) * (nwg >> 3) + (bid >> 3)) : bid;
    const int mt = swb / ntile, nt = swb - mt * ntile;

    const unsigned char* Abase = A  + (size_t)(mt * 64) * K;
    const unsigned char* Bbase = Bt + (size_t)(nt * 128) * K;

    {
        int rB = tid >> 2;
        int gpB = (tid & 3) ^ ((rB >> 1) & 3);
#pragma unroll
        for (int kb = 0; kb < 6; ++kb)
            gload_lds16(Bbase + (size_t)rB * K + kb * 64 + gpB * 16, &Bls[kb * 8192 + tid * 16]);
        if (tid < 256) {
            int rA = tid >> 2;
            int gpA = (tid & 3) ^ ((rA >> 1) & 3);
#pragma unroll
            for (int kb = 0; kb < 6; ++kb)
                gload_lds16(Abase + (size_t)rA * K + kb * 64 + gpA * 16, &Als[kb * 4096 + tid * 16]);
        }
    }
    asm volatile("s_waitcnt vmcnt(0)" ::: "memory");
    __builtin_amdgcn_s_barrier();

    const int fr = lane & 15, kq = lane >> 4;
    const int cb = (kq ^ ((fr >> 1) & 3)) << 4;

    f32x4 acc[4] = {};
#pragma unroll
    for (int kb = 0; kb < 6; ++kb) {
        longx2 a[4], b;
        b = *(const longx2*)(&Bls[kb * 8192 + (wid * 16 + fr) * 64 + cb]);
#pragma unroll
        for (int m = 0; m < 4; ++m)
            a[m] = *(const longx2*)(&Als[kb * 4096 + (m * 16 + fr) * 64 + cb]);
#pragma unroll
        for (int ks = 0; ks < 2; ++ks)
#pragma unroll
            for (int m = 0; m < 4; ++m)
                acc[m] = __builtin_amdgcn_mfma_f32_16x16x32_fp8_fp8(b[ks], a[m][ks], acc[m], 0, 0, 0);
    }

    const int row0 = mt * 64;
    const int col0 = nt * 128 + wid * 16;
    const int rl = lane & 15;
    const int cq = (lane >> 4) << 2;
    const int col = col0 + cq;
#pragma unroll
    for (int m = 0; m < 4; ++m) {
        int row = row0 + m * 16 + rl;
        f32x4 v = acc[m];
        if constexpr (MODE == 0) {
            int pk = 0;
            pk = __builtin_amdgcn_cvt_pk_fp8_f32(v[0], v[1], pk, false);
            pk = __builtin_amdgcn_cvt_pk_fp8_f32(v[2], v[3], pk, true);
            *(int*)(outb8 + (size_t)row * N + col) = pk;
        } else if constexpr (MODE == 1) {
            size_t o = (size_t)tokmap[row] * 384 + col;
            f32x4 rv = *(const f32x4*)&resid[o];
            f32x4 bb = *(const f32x4*)&bias[col];
            f32x4 ov = rv + v + bb;
            *(f32x4*)&outf[o] = ov;
        } else {
            f32x4 bb = *(const f32x4*)&bias[col];
            float g4[4];
#pragma unroll
            for (int r = 0; r < 4; ++r) {
                float t2 = v[r] + bb[r];
                float e  = __expf(-1.702f * t2);
                g4[r] = t2 * __builtin_amdgcn_rcpf(1.f + e);
            }
            int pk = 0;
            pk = __builtin_amdgcn_cvt_pk_fp8_f32(g4[0], g4[1], pk, false);
            pk = __builtin_amdgcn_cvt_pk_fp8_f32(g4[2], g4[3], pk, true);
            *(int*)(outb8 + (size_t)row * N + kpos(col)) = pk;
        }
    }
}

// ---------------- fp8 ring GEMM (FFN2, K=1536): 128x128 tile, 8 waves, single-barrier ring ------
// NBUF=4/DEPTH=2, BK=64; LDS 64 KB -> 2 blocks/CU x 8 waves = 4 waves/SIMD (2352 blocks,
// same per-block staging amortization as the 156us 4-wave config, isolates waves/SIMD).
// Staging uniform: every thread 1 A-load + 1 B-load per stage -> wave-uniform counted vmcnt.
template <int NBUF, int DEPTH>
__global__ __launch_bounds__(512, 4) void gemm_f8_ring8(const unsigned char* __restrict__ A,
                                                        const unsigned char* __restrict__ Bt,
                                                        int M, int N, int K,
                                                        const float* __restrict__ bias,
                                                        const float* __restrict__ resid,
                                                        float* __restrict__ outf) {
    static_assert(NBUF >= DEPTH + 2, "single-barrier ring needs NBUF >= DEPTH+2");
    __shared__ unsigned char As[NBUF][128 * 64];   // 8 KB each
    __shared__ unsigned char Bs[NBUF][128 * 64];   // 8 KB each
    const int tid = threadIdx.x;                   // 0..511
    const int wid = tid >> 6, lane = tid & 63;
    const int ntile = N >> 7;

    int bid = blockIdx.x;
    int nwg = gridDim.x;
    int swb = ((nwg & 7) == 0) ? ((bid & 7) * (nwg >> 3) + (bid >> 3)) : bid;
    const int mt = swb / ntile, nt = swb - mt * ntile;
    const int wr = wid >> 2, wc = wid & 3;   // 2 wave-rows x 4 wave-cols

    f32x4 acc[4][2] = {};

    const unsigned char* Abase = A  + (size_t)(mt * 128) * K;
    const unsigned char* Bbase = Bt + (size_t)(nt * 128) * K;

    auto stage = [&](int buf, int k0) {
        int r  = tid >> 2;                       // 0..127
        int gp = (tid & 3) ^ ((r >> 1) & 3);     // pre-swizzled 16B chunk
        gload_lds16(Abase + (size_t)r * K + k0 + gp * 16, &As[buf][tid * 16]);
        gload_lds16(Bbase + (size_t)r * K + k0 + gp * 16, &Bs[buf][tid * 16]);
    };

    const int fr = lane & 15, kq = lane >> 4;
    const int cb = (kq ^ ((fr >> 1) & 3)) << 4;
    const int rowA = wr * 64 + fr;
    const int rowB = wc * 32 + fr;

    const int nk = K >> 6;   // 24 for K=1536
    stage(0, 0);
    stage(1, 64);

    for (int t = 0; t < nk; ++t) {
        const int cur = t % NBUF;
        if (t + DEPTH < nk) {
            stage((t + DEPTH) % NBUF, (t + DEPTH) << 6);
            asm volatile("s_waitcnt vmcnt(4)" ::: "memory");   // keep 2 stages (4 loads) in flight
        } else if (t + 1 < nk) {
            asm volatile("s_waitcnt vmcnt(2)" ::: "memory");
        } else {
            asm volatile("s_waitcnt vmcnt(0)" ::: "memory");
        }
        __builtin_amdgcn_s_barrier();   // tile t resident for every wave; releases ring slot

        longx2 a[4], b[2];
#pragma unroll
        for (int m = 0; m < 4; ++m)
            a[m] = *(const longx2*)(&As[cur][(rowA + m * 16) * 64 + cb]);
#pragma unroll
        for (int n = 0; n < 2; ++n)
            b[n] = *(const longx2*)(&Bs[cur][(rowB + n * 16) * 64 + cb]);
#pragma unroll
        for (int ks = 0; ks < 2; ++ks)
#pragma unroll
            for (int m = 0; m < 4; ++m)
#pragma unroll
                for (int n = 0; n < 2; ++n)
                    acc[m][n] = __builtin_amdgcn_mfma_f32_16x16x32_fp8_fp8(b[n][ks], a[m][ks], acc[m][n], 0, 0, 0);

        asm volatile("s_waitcnt lgkmcnt(0)" ::: "memory");
    }

    const int row0 = mt * 128 + wr * 64;
    const int col0 = nt * 128 + wc * 32;
    const int rl = lane & 15;
    const int cq = (lane >> 4) << 2;
#pragma unroll
    for (int m = 0; m < 4; ++m) {
        int row = row0 + m * 16 + rl;
#pragma unroll
        for (int n = 0; n < 2; ++n) {
            int col = col0 + n * 16 + cq;
            f32x4 v = acc[m][n];
            size_t o = (size_t)row * N + col;
            f32x4 rv = *(const f32x4*)&resid[o];
            f32x4 bb = *(const f32x4*)&bias[col];
            f32x4 ov = rv + v + bb;
            *(f32x4*)&outf[o] = ov;
        }
    }
}

// ---------------- MFMA attention: fp8 QK^T, bf16 PV; O out fp8 k-interleaved ----------------
__global__ __launch_bounds__(256, 2) void attn_kernel(const unsigned char* __restrict__ QKV8,
                                                      const float* __restrict__ Btab,
                                                      unsigned char* __restrict__ O8) {
    __shared__ char lds[8192 + 16384 + 32768];   // Kl 8K | Vl 16K | Pl 32K = 56 KB
    char* Kl = lds;
    char* Vl = lds + 8192;
    char* Pl = lds + 24576;

    const int w   = blockIdx.x;
    const int tid = threadIdx.x, wid = tid >> 6, lane = tid & 63;
    const int fr  = lane & 15, kq = lane >> 4;
    const size_t base = (size_t)w * 49 * 1152;
    const int widx = w & 63, wi = widx >> 3, wj = widx & 7;
    const int cls = ((wi == 7) ? 2 : 0) | ((wj == 7) ? 1 : 0);
    const float* tb = Btab + (size_t)cls * 12 * 4096;
    constexpr float SCL = 0.17677669529663687f;

    for (int R = 0; R < 3; ++R) {
        if (R) __syncthreads();
        {
            f32x4 z = {};
#pragma unroll
            for (int j = 0; j < 6; ++j) *(f32x4*)(lds + j * 4096 + tid * 16) = z;
        }
        __syncthreads();
        {
            int hh = tid >> 6, h = R * 4 + hh;
#pragma unroll
            for (int it = 0; it < 4; ++it) {
                int i = (tid & 63) + it * 64;
                if (i < 196) {
                    int m = i >> 2, c = i & 3;
                    long k8 = *(const long*)(QKV8 + base + (size_t)m * 1152 + 384 + h * 32 + c * 8);
                    int s = c ^ (m & 3) ^ ((m >> 2) & 3);
                    *(long*)(Kl + hh * 2048 + m * 32 + s * 8) = k8;
                    long v8 = *(const long*)(QKV8 + base + (size_t)m * 1152 + 768 + h * 32 + c * 8);
                    int lo = (int)v8, hi = (int)(v8 >> 32);
                    float vf[8];
                    vf[0] = __builtin_amdgcn_cvt_f32_fp8(lo, 0);
                    vf[1] = __builtin_amdgcn_cvt_f32_fp8(lo, 1);
                    vf[2] = __builtin_amdgcn_cvt_f32_fp8(lo, 2);
                    vf[3] = __builtin_amdgcn_cvt_f32_fp8(lo, 3);
                    vf[4] = __builtin_amdgcn_cvt_f32_fp8(hi, 0);
                    vf[5] = __builtin_amdgcn_cvt_f32_fp8(hi, 1);
                    vf[6] = __builtin_amdgcn_cvt_f32_fp8(hi, 2);
                    vf[7] = __builtin_amdgcn_cvt_f32_fp8(hi, 3);
#pragma unroll
                    for (int j = 0; j < 8; ++j) {
                        int d = c * 8 + j;
                        *(unsigned short*)(Vl + hh * 4096 + d * 128 +
                                           (((m >> 3) ^ (d & 7)) * 16) + (m & 7) * 2) = f2b(vf[j]);
                    }
                }
            }
        }
        __syncthreads();

        const int h = R * 4 + wid;
        const float* tbh = tb + h * 4096;

        long aq[4], bk[4];
#pragma unroll
        for (int mi = 0; mi < 4; ++mi) {
            int row = mi * 16 + fr; if (row > 48) row = 48;
            aq[mi] = *(const long*)(QKV8 + base + (size_t)row * 1152 + h * 32 + kq * 8);
        }
#pragma unroll
        for (int ni = 0; ni < 4; ++ni) {
            int rk = ni * 16 + fr;
            bk[ni] = *(const long*)(Kl + wid * 2048 + rk * 32 +
                                    ((kq ^ (rk & 3) ^ ((rk >> 2) & 3)) * 8));
        }
        f32x4 s[4][4] = {};
#pragma unroll
        for (int mi = 0; mi < 4; ++mi)
#pragma unroll
            for (int ni = 0; ni < 4; ++ni)
                s[mi][ni] = __builtin_amdgcn_mfma_f32_16x16x32_fp8_fp8(bk[ni], aq[mi], s[mi][ni], 0, 0, 0);

        float linv_[4];
#pragma unroll
        for (int mi = 0; mi < 4; ++mi) {
            int row = mi * 16 + fr;
            const float* tr = tbh + row * 64 + kq * 4;
            f32x4 sv[4];
            float mx = -1e30f;
#pragma unroll
            for (int ni = 0; ni < 4; ++ni) {
                f32x4 bb = *(const f32x4*)&tr[ni * 16];
                sv[ni] = s[mi][ni] * SCL + bb;
                mx = fmaxf(mx, fmaxf(fmaxf(sv[ni][0], sv[ni][1]), fmaxf(sv[ni][2], sv[ni][3])));
            }
            mx = fmaxf(mx, __shfl_xor(mx, 16, 64));
            mx = fmaxf(mx, __shfl_xor(mx, 32, 64));
            float sm = 0.f;
#pragma unroll
            for (int ni = 0; ni < 4; ++ni)
#pragma unroll
                for (int r = 0; r < 4; ++r) { sv[ni][r] = __expf(sv[ni][r] - mx); sm += sv[ni][r]; }
            sm += __shfl_xor(sm, 16, 64);
            sm += __shfl_xor(sm, 32, 64);
            linv_[mi] = __builtin_amdgcn_rcpf(sm);
#pragma unroll
            for (int ni = 0; ni < 4; ++ni) {
                int colb = ni * 16 + kq * 4;
                int phys = (colb >> 3) ^ (row & 7);
                u16x4 pk;
#pragma unroll
                for (int r = 0; r < 4; ++r) pk[r] = f2b(sv[ni][r]);
                *(u16x4*)(Pl + wid * 8192 + row * 128 + phys * 16 + (colb & 7) * 2) = pk;
            }
        }
        asm volatile("s_waitcnt lgkmcnt(0)" ::: "memory");
        __builtin_amdgcn_sched_barrier(0);

        f32x4 oacc[4][2] = {};
#pragma unroll
        for (int sl = 0; sl < 2; ++sl) {
            bf16x8 bv[2];
#pragma unroll
            for (int ni = 0; ni < 2; ++ni) {
                int d = ni * 16 + fr;
                bv[ni] = *(const bf16x8*)(Vl + wid * 4096 + d * 128 + (((sl * 4 + kq) ^ (d & 7)) * 16));
            }
#pragma unroll
            for (int mi = 0; mi < 4; ++mi) {
                int row = mi * 16 + fr;
                bf16x8 ap = *(const bf16x8*)(Pl + wid * 8192 + row * 128 + (((sl * 4 + kq) ^ (row & 7)) * 16));
#pragma unroll
                for (int ni = 0; ni < 2; ++ni)
                    oacc[mi][ni] = __builtin_amdgcn_mfma_f32_16x16x32_bf16(bv[ni], ap, oacc[mi][ni], 0, 0, 0);
            }
        }

#pragma unroll
        for (int mi = 0; mi < 4; ++mi) {
            int row = mi * 16 + fr;
            if (row < 49) {
                float li = linv_[mi];
                unsigned char* opb = O8 + (size_t)(w * 49 + row) * 384;
#pragma unroll
                for (int ni = 0; ni < 2; ++ni) {
                    int c = h * 32 + ni * 16 + kq * 4;
                    int pk = 0;
                    pk = __builtin_amdgcn_cvt_pk_fp8_f32(oacc[mi][ni][0] * li, oacc[mi][ni][1] * li, pk, false);
                    pk = __builtin_amdgcn_cvt_pk_fp8_f32(oacc[mi][ni][2] * li, oacc[mi][ni][3] * li, pk, true);
                    *(int*)(opb + kpos(c)) = pk;
                }
            }
        }
    }
}

extern "C" void kernel_launch(void* const* d_in, const int* in_sizes, int n_in,
                              void* d_out, int out_size, void* d_ws, size_t ws_size,
                              hipStream_t stream) {
    const float* x     = (const float*)d_in[0];
    const int*   rel   = (const int*)  d_in[3];
    const float* rpb   = (const float*)d_in[4];
    const float* qkvw  = (const float*)d_in[5];
    const float* projw = (const float*)d_in[6];
    const float* projb = (const float*)d_in[7];
    const float* n1g   = (const float*)d_in[8];
    const float* n1b   = (const float*)d_in[9];
    const float* n2g   = (const float*)d_in[10];
    const float* n2b   = (const float*)d_in[11];
    const float* w1    = (const float*)d_in[12];
    const float* b1    = (const float*)d_in[13];
    const float* w2    = (const float*)d_in[14];
    const float* b2    = (const float*)d_in[15];
    float* out = (float*)d_out;

    const int T = in_sizes[0] / 384;   // 100352

    char* ws = (char*)d_ws;
    size_t off = 0;
    auto alloc = [&](size_t bytes) {
        char* p = ws + off;
        off += (bytes + 255) & ~(size_t)255;
        return p;
    };
    unsigned char* Wq8  = (unsigned char*)alloc((size_t)1152 * 384);
    unsigned char* Wp8  = (unsigned char*)alloc((size_t)384 * 384);
    unsigned char* W18  = (unsigned char*)alloc((size_t)1536 * 384);
    unsigned char* W28  = (unsigned char*)alloc((size_t)384 * 1536);
    float*         Btab = (float*)       alloc((size_t)4 * 12 * 4096 * 4);
    int*           Tmap = (int*)         alloc((size_t)T * 4);
    unsigned char* slotA = (unsigned char*)alloc((size_t)T * 384);    // X1_8 -> O8 -> X2_8
    unsigned char* slotB = (unsigned char*)alloc((size_t)T * 1536);   // QKV8 -> F8

    unsigned char* X1   = slotA;
    unsigned char* O8   = slotA;
    unsigned char* X2   = slotA;
    unsigned char* QKV8 = slotB;
    unsigned char* F8   = slotB;
    float*         Hh   = out;

    wprep8<<<dim3((1152 * 384 + 255) / 256), 256, 0, stream>>>(qkvw, Wq8, 384, 1152);
    wprep8<<<dim3((384 * 384 + 255) / 256),  256, 0, stream>>>(projw, Wp8, 384, 384);
    wprep8<<<dim3((384 * 1536 + 255) / 256), 256, 0, stream>>>(w1, W18, 384, 1536);
    wprep8<<<dim3((1536 * 384 + 255) / 256), 256, 0, stream>>>(w2, W28, 1536, 384);
    btab_build<<<dim3((4 * 12 * 4096 + 255) / 256), 256, 0, stream>>>(rel, rpb, Btab);
    tokmap_build<<<dim3((T + 255) / 256), 256, 0, stream>>>(Tmap, T);

    // LN1 + shifted-window gather -> X1 (fp8 k-interleaved)
    ln_kernel<1><<<dim3(T / 4), 256, 0, stream>>>(x, n1g, n1b, X1, T);
    // QKV projection -> QKV8 (fp8 PLAIN; full-K 8-wave)
    gemm_f8_fullk<0><<<dim3((T / 64) * (1152 / 128)), 512, 0, stream>>>(
        X1, Wq8, T, 1152, 384, nullptr, nullptr, nullptr, QKV8, nullptr);
    // MFMA windowed attention (fp8 QK^T, bf16 PV) -> O8 (fp8 k-interleaved)
    attn_kernel<<<dim3(T / 49), 256, 0, stream>>>(QKV8, Btab, O8);
    // proj + bias + tokmap remap + residual -> Hh (= d_out, fp32; full-K 8-wave)
    gemm_f8_fullk<1><<<dim3((T / 64) * (384 / 128)), 512, 0, stream>>>(
        O8, Wp8, T, 384, 384, projb, x, Tmap, nullptr, Hh);
    // LN2 -> X2 (fp8 k-interleaved)
    ln_kernel<0><<<dim3(T / 4), 256, 0, stream>>>(Hh, n2g, n2b, X2, T);
    // FFN1 + bias + sigmoid-GELU -> F8 (fp8 k-interleaved; full-K 8-wave)
    gemm_f8_fullk<2><<<dim3((T / 64) * (1536 / 128)), 512, 0, stream>>>(
        X2, W18, T, 1536, 384, b1, nullptr, nullptr, F8, nullptr);
    // FFN2 + bias + residual -> out (fp32, in-place RMW; 128x128 8-wave single-barrier ring)
    gemm_f8_ring8<4, 2><<<dim3((T / 128) * (384 / 128)), 512, 0, stream>>>(
        F8, W28, T, 384, 1536, b2, Hh, out);
}